// Round 1
// baseline (242.141 us; speedup 1.0000x reference)
//
#include <hip/hip_runtime.h>
#include <stdint.h>

#define NN 4096
#define KIN 512
#define NH 8
#define DF 128
#define HID 1024

typedef __attribute__((ext_vector_type(8))) short bf16x8;
typedef __attribute__((ext_vector_type(4))) float f32x4;
typedef __attribute__((ext_vector_type(8))) unsigned short u16x8;
typedef unsigned short u16;

__device__ __forceinline__ u16 f2bf(float x){
  unsigned int u = __float_as_uint(x);
  return (u16)((u + 0x7fffu + ((u >> 16) & 1u)) >> 16);
}

__device__ __forceinline__ void gload16(const void* g, void* lds){
  __builtin_amdgcn_global_load_lds(
      (const __attribute__((address_space(1))) unsigned int*)g,
      (__attribute__((address_space(3))) unsigned int*)lds, 16, 0, 0);
}

// ---------------- kernel 1: pack adjacency to bitmask (4096x512 bytes) ------
__global__ __launch_bounds__(256) void k_pack(const int* __restrict__ adj,
                                              unsigned long long* __restrict__ bm){
  int idx = blockIdx.x * 256 + threadIdx.x;
  int v = adj[idx] != 0;
  unsigned long long m = __ballot(v);
  if ((threadIdx.x & 63) == 0) bm[idx >> 6] = m;
}

// ---------------- kernel 2: bf16 convert X -> A2, W^T -> WT -----------------
__global__ __launch_bounds__(256) void k_conv(const float* __restrict__ X,
                                              const float* __restrict__ W,
                                              u16* __restrict__ A2,
                                              u16* __restrict__ WT){
  int idx = blockIdx.x * 256 + threadIdx.x;
  if (idx < NN * KIN) A2[idx] = f2bf(X[idx]);
  if (idx < HID * KIN){
    int n = idx / KIN, k = idx % KIN;
    WT[idx] = f2bf(W[k * HID + n]);
  }
}

// ---------------- kernel 3: h = X @ W  (bf16 MFMA, 128x128 tile) ------------
__global__ __launch_bounds__(256) void k_gemm(const u16* __restrict__ A2,
                                              const u16* __restrict__ BT,
                                              float* __restrict__ C){
  __shared__ u16 As[8192], Bs[8192];  // [128 rows][64 k], XOR-swizzled rows
  const int tid = threadIdx.x;
  const int l = tid & 63, w = tid >> 6;
  const int wr = w >> 1, wc = w & 1;
  const int ib = blockIdx.x >> 3, nb = blockIdx.x & 7;
  const int p = l >> 4;
  f32x4 acc[4][4] = {};
  for (int k0 = 0; k0 < KIN; k0 += 64){
    __syncthreads();
    #pragma unroll
    for (int q = 0; q < 4; q++){
      int beta = ((q << 8) + tid) << 4;
      int row = beta >> 7, inner = beta & 127;
      int gin = inner ^ ((row & 7) << 4);
      gload16(A2 + (size_t)(ib * 128 + row) * KIN + k0 + (gin >> 1), (char*)As + beta);
      gload16(BT + (size_t)(nb * 128 + row) * KIN + k0 + (gin >> 1), (char*)Bs + beta);
    }
    __syncthreads();
    #pragma unroll
    for (int kk = 0; kk < 2; kk++){
      bf16x8 af[4], bfv[4];
      const int kb = ((kk << 5) + (p << 3)) << 1;
      #pragma unroll
      for (int m = 0; m < 4; m++){
        int r = wr * 64 + m * 16 + (l & 15);
        af[m] = *(const bf16x8*)((const char*)As + r * 128 + (kb ^ ((r & 7) << 4)));
      }
      #pragma unroll
      for (int n = 0; n < 4; n++){
        int r = wc * 64 + n * 16 + (l & 15);
        bfv[n] = *(const bf16x8*)((const char*)Bs + r * 128 + (kb ^ ((r & 7) << 4)));
      }
      #pragma unroll
      for (int m = 0; m < 4; m++)
        #pragma unroll
        for (int n = 0; n < 4; n++)
          acc[m][n] = __builtin_amdgcn_mfma_f32_16x16x32_bf16(af[m], bfv[n], acc[m][n], 0, 0, 0);
    }
  }
  #pragma unroll
  for (int m = 0; m < 4; m++)
    #pragma unroll
    for (int n = 0; n < 4; n++)
      #pragma unroll
      for (int r4 = 0; r4 < 4; r4++){
        int row = ib * 128 + wr * 64 + m * 16 + p * 4 + r4;
        int col = nb * 128 + wc * 64 + n * 16 + (l & 15);
        C[(size_t)row * HID + col] = acc[m][n][r4];
      }
}

// ---------------- kernel 4: l, r and exp factors per (head,row) -------------
__global__ __launch_bounds__(256) void k_lr(const float* __restrict__ h,
                                            const float* __restrict__ a,
                                            float* __restrict__ L,  float* __restrict__ EL,
                                            float* __restrict__ EL2, float* __restrict__ R,
                                            float* __restrict__ ER, float* __restrict__ ER2){
  const int i = blockIdx.x;
  const int t = threadIdx.x;
  const int hd = t >> 5, l32 = t & 31;
  const int f = l32 << 2;
  const float4 hv = *(const float4*)(h + (size_t)i * HID + hd * DF + f);
  float pl = hv.x * a[(f + 0) * NH + hd] + hv.y * a[(f + 1) * NH + hd]
           + hv.z * a[(f + 2) * NH + hd] + hv.w * a[(f + 3) * NH + hd];
  float pr = hv.x * a[(128 + f + 0) * NH + hd] + hv.y * a[(128 + f + 1) * NH + hd]
           + hv.z * a[(128 + f + 2) * NH + hd] + hv.w * a[(128 + f + 3) * NH + hd];
  #pragma unroll
  for (int s = 1; s < 32; s <<= 1){
    pl += __shfl_xor(pl, s);
    pr += __shfl_xor(pr, s);
  }
  if (l32 == 0){
    int idx = hd * NN + i;
    L[idx]  = pl;            R[idx]  = pr;
    EL[idx] = expf(pl);      ER[idx] = expf(pr);
    EL2[idx]= expf(0.2f*pl); ER2[idx]= expf(0.2f*pr);
  }
}

// ---------------- kernel 5: HT[f][j] = bf16(h[j][f])  (transpose) -----------
__global__ __launch_bounds__(256) void k_tr(const float* __restrict__ h,
                                            u16* __restrict__ HT){
  __shared__ u16 T[64][80];  // stride 160B (16B-aligned rows)
  const int it = blockIdx.x & 63, ft = blockIdx.x >> 6;
  const int i0 = it * 64, f0 = ft * 64;
  const int t = threadIdx.x;
  const int r = t >> 4, c = (t & 15) << 2;
  #pragma unroll
  for (int q = 0; q < 4; q++){
    int row = r + q * 16;
    float4 v = *(const float4*)(h + (size_t)(i0 + row) * HID + f0 + c);
    T[c + 0][row] = f2bf(v.x);
    T[c + 1][row] = f2bf(v.y);
    T[c + 2][row] = f2bf(v.z);
    T[c + 3][row] = f2bf(v.w);
  }
  __syncthreads();
  const int fr = t >> 2, c0 = (t & 3) << 4;
  u16x8 v0 = *(const u16x8*)&T[fr][c0];
  u16x8 v1 = *(const u16x8*)&T[fr][c0 + 8];
  *(u16x8*)(HT + (size_t)(f0 + fr) * NN + i0 + c0)     = v0;
  *(u16x8*)(HT + (size_t)(f0 + fr) * NN + i0 + c0 + 8) = v1;
}

// ---------------- kernel 6: masked-softmax aggregation (the main one) -------
// grid 256 = 8 heads x 32 i-blocks; 512 threads = 8 waves, wave w owns rows
// i0 + w*16 .. +16, all 128 f. Weights generated in registers as MFMA
// A-fragments; H^T tile double-buffered in LDS (XOR-swizzled).
__global__ __launch_bounds__(512) void k_agg(const u16* __restrict__ HT,
                                             const unsigned char* __restrict__ bm,
                                             const float* __restrict__ L,
                                             const float* __restrict__ EL,
                                             const float* __restrict__ EL2,
                                             const float* __restrict__ R,
                                             const float* __restrict__ ER,
                                             const float* __restrict__ ER2,
                                             float* __restrict__ out){
  __shared__ u16 Hs[2 * 8192];  // 2 x [128 f][64 j] bf16, swizzled
  const int hd = blockIdx.x >> 5, ib = blockIdx.x & 31;
  const int i0 = ib * 128;
  const int tid = threadIdx.x;
  const int w = tid >> 6, l = tid & 63;
  const int p = l >> 4;
  const int row_l = (w << 4) + (l & 15);
  const int gi = i0 + row_l;
  const float lv  = L  [hd * NN + gi];
  const float elv = EL [hd * NN + gi];
  const float el2v= EL2[hd * NN + gi];
  const float* Rr  = R   + hd * NN;
  const float* ERr = ER  + hd * NN;
  const float* GRr = ER2 + hd * NN;
  const unsigned char* bmrow = bm + (size_t)gi * 512;
  const u16* src = HT + (size_t)hd * DF * NN;
  float dsum = 0.f;
  f32x4 acc[8] = {};

  auto stage = [&](int d, int j0s){
    #pragma unroll
    for (int q = 0; q < 2; q++){
      int beta = ((q << 9) + tid) << 4;
      int fr = beta >> 7, inner = beta & 127;
      int gin = inner ^ ((fr & 7) << 4);
      gload16(src + (size_t)fr * NN + j0s + (gin >> 1), (char*)Hs + d * 16384 + beta);
    }
  };

  stage(0, 0);
  __syncthreads();

  for (int jt = 0; jt < 64; ++jt){
    const int j0 = jt << 6;
    const int cur = jt & 1;
    if (jt < 63) stage(cur ^ 1, j0 + 64);

    // generate weight A-fragments for rows row_l, j in [j0, j0+64)
    bf16x8 af[2];
    #pragma unroll
    for (int kk = 0; kk < 2; kk++){
      const int jb = j0 + (kk << 5) + (p << 3);
      const float4 rv0 = *(const float4*)(Rr  + jb);
      const float4 rv1 = *(const float4*)(Rr  + jb + 4);
      const float4 ev0 = *(const float4*)(ERr + jb);
      const float4 ev1 = *(const float4*)(ERr + jb + 4);
      const float4 gv0 = *(const float4*)(GRr + jb);
      const float4 gv1 = *(const float4*)(GRr + jb + 4);
      const unsigned int bbits = bmrow[jb >> 3];
      const float rarr[8] = {rv0.x, rv0.y, rv0.z, rv0.w, rv1.x, rv1.y, rv1.z, rv1.w};
      const float earr[8] = {ev0.x, ev0.y, ev0.z, ev0.w, ev1.x, ev1.y, ev1.z, ev1.w};
      const float garr[8] = {gv0.x, gv0.y, gv0.z, gv0.w, gv1.x, gv1.y, gv1.z, gv1.w};
      bf16x8 av;
      #pragma unroll
      for (int e = 0; e < 8; e++){
        float s  = lv + rarr[e];
        bool pos = s > 0.f;
        float w1 = pos ? elv : el2v;
        float w2 = pos ? earr[e] : garr[e];
        float wq = w1 * w2;
        wq = ((bbits >> e) & 1u) ? wq : 0.f;
        dsum += wq;
        av[e] = (short)f2bf(wq);
      }
      af[kk] = av;
    }

    // MFMA: acc[n] += W_frag x H^T fragments
    const char* hb = (const char*)Hs + cur * 16384;
    #pragma unroll
    for (int kk = 0; kk < 2; kk++){
      const int kb = ((kk << 5) + (p << 3)) << 1;
      #pragma unroll
      for (int n = 0; n < 8; n++){
        const int fr = (n << 4) + (l & 15);
        bf16x8 bfr = *(const bf16x8*)(hb + fr * 128 + (kb ^ ((fr & 7) << 4)));
        acc[n] = __builtin_amdgcn_mfma_f32_16x16x32_bf16(af[kk], bfr, acc[n], 0, 0, 0);
      }
    }
    __syncthreads();
  }

  // full row denominators: sum over the 4 k-octet lane groups
  dsum += __shfl_xor(dsum, 16);
  dsum += __shfl_xor(dsum, 32);

  const int rowbase = i0 + (w << 4);
  #pragma unroll
  for (int r4 = 0; r4 < 4; r4++){
    float dr = __shfl(dsum, (p << 2) + r4);   // lanes 0..15 hold rows 0..15
    float rinv = 1.0f / dr;
    const int grow = rowbase + (p << 2) + r4;
    float* orow = out + (size_t)grow * HID + hd * DF;
    #pragma unroll
    for (int n = 0; n < 8; n++){
      float v = acc[n][r4] * rinv;
      v = v > 0.f ? v : (expf(v) - 1.0f);   // ELU, alpha=1
      orow[(n << 4) + (l & 15)] = v;
    }
  }
}

extern "C" void kernel_launch(void* const* d_in, const int* in_sizes, int n_in,
                              void* d_out, int out_size, void* d_ws, size_t ws_size,
                              hipStream_t stream) {
  const float* X   = (const float*)d_in[0];
  const int*   adj = (const int*)d_in[1];
  const float* W   = (const float*)d_in[2];
  const float* a   = (const float*)d_in[3];
  float* out = (float*)d_out;

  char* ws = (char*)d_ws;
  size_t off = 0;
  float* h  = (float*)(ws + off);        off += (size_t)NN * HID * 4;   // 16.78 MB
  u16*   A2 = (u16*)(ws + off);          off += (size_t)NN * KIN * 2;   //  4.19 MB
  u16*   WT = (u16*)(ws + off);          off += (size_t)HID * KIN * 2;  //  1.05 MB
  u16*   HT = (u16*)(ws + off);          off += (size_t)HID * NN * 2;   //  8.39 MB
  unsigned char* bmp = (unsigned char*)(ws + off); off += (size_t)NN * 512; // 2.10 MB
  float* L   = (float*)(ws + off);       off += (size_t)NH * NN * 4;
  float* EL  = (float*)(ws + off);       off += (size_t)NH * NN * 4;
  float* EL2 = (float*)(ws + off);       off += (size_t)NH * NN * 4;
  float* R   = (float*)(ws + off);       off += (size_t)NH * NN * 4;
  float* ER  = (float*)(ws + off);       off += (size_t)NH * NN * 4;
  float* ER2 = (float*)(ws + off);       off += (size_t)NH * NN * 4;    // total ~33.3 MB

  k_pack<<<dim3(NN * NN / 256), dim3(256), 0, stream>>>(adj, (unsigned long long*)bmp);
  k_conv<<<dim3(NN * KIN / 256), dim3(256), 0, stream>>>(X, W, A2, WT);
  k_gemm<<<dim3(256), dim3(256), 0, stream>>>(A2, WT, h);
  k_lr  <<<dim3(NN), dim3(256), 0, stream>>>(h, a, L, EL, EL2, R, ER, ER2);
  k_tr  <<<dim3(1024), dim3(256), 0, stream>>>(h, HT);
  k_agg <<<dim3(256), dim3(512), 0, stream>>>(HT, bmp, L, EL, EL2, R, ER, ER2, out);
}

// Round 2
// 182.518 us; speedup vs baseline: 1.3267x; 1.3267x over previous
//
#include <hip/hip_runtime.h>
#include <stdint.h>

#define NN 4096
#define KIN 512
#define NH 8
#define DF 128
#define HID 1024

typedef __attribute__((ext_vector_type(8))) short bf16x8;
typedef __attribute__((ext_vector_type(4))) float f32x4;
typedef __attribute__((ext_vector_type(8))) unsigned short u16x8;
typedef unsigned short u16;

__device__ __forceinline__ u16 f2bf(float x){
  unsigned int u = __float_as_uint(x);
  return (u16)((u + 0x7fffu + ((u >> 16) & 1u)) >> 16);
}

__device__ __forceinline__ void gload16(const void* g, void* lds){
  __builtin_amdgcn_global_load_lds(
      (const __attribute__((address_space(1))) unsigned int*)g,
      (__attribute__((address_space(3))) unsigned int*)lds, 16, 0, 0);
}

// ---------------- kernel 1: pack adjacency to bitmask (4096x512 bytes) ------
__global__ __launch_bounds__(256) void k_pack(const int* __restrict__ adj,
                                              unsigned long long* __restrict__ bm){
  int idx = blockIdx.x * 256 + threadIdx.x;
  int v = adj[idx] != 0;
  unsigned long long m = __ballot(v);
  if ((threadIdx.x & 63) == 0) bm[idx >> 6] = m;
}

// ---------------- kernel 2: bf16 convert X -> A2, W^T -> WT -----------------
__global__ __launch_bounds__(256) void k_conv(const float* __restrict__ X,
                                              const float* __restrict__ W,
                                              u16* __restrict__ A2,
                                              u16* __restrict__ WT){
  int idx = blockIdx.x * 256 + threadIdx.x;
  if (idx < NN * KIN) A2[idx] = f2bf(X[idx]);
  if (idx < HID * KIN){
    int n = idx / KIN, k = idx % KIN;
    WT[idx] = f2bf(W[k * HID + n]);
  }
}

// ---------------- kernel 3: h = X @ W  (bf16 MFMA, 128x128 tile) ------------
__global__ __launch_bounds__(256) void k_gemm(const u16* __restrict__ A2,
                                              const u16* __restrict__ BT,
                                              float* __restrict__ C){
  __shared__ u16 As[8192], Bs[8192];  // [128 rows][64 k], XOR-swizzled rows
  const int tid = threadIdx.x;
  const int l = tid & 63, w = tid >> 6;
  const int wr = w >> 1, wc = w & 1;
  const int ib = blockIdx.x >> 3, nb = blockIdx.x & 7;
  const int p = l >> 4;
  f32x4 acc[4][4] = {};
  for (int k0 = 0; k0 < KIN; k0 += 64){
    __syncthreads();
    #pragma unroll
    for (int q = 0; q < 4; q++){
      int beta = ((q << 8) + tid) << 4;
      int row = beta >> 7, inner = beta & 127;
      int gin = inner ^ ((row & 7) << 4);
      gload16(A2 + (size_t)(ib * 128 + row) * KIN + k0 + (gin >> 1), (char*)As + beta);
      gload16(BT + (size_t)(nb * 128 + row) * KIN + k0 + (gin >> 1), (char*)Bs + beta);
    }
    __syncthreads();
    #pragma unroll
    for (int kk = 0; kk < 2; kk++){
      bf16x8 af[4], bfv[4];
      const int kb = ((kk << 5) + (p << 3)) << 1;
      #pragma unroll
      for (int m = 0; m < 4; m++){
        int r = wr * 64 + m * 16 + (l & 15);
        af[m] = *(const bf16x8*)((const char*)As + r * 128 + (kb ^ ((r & 7) << 4)));
      }
      #pragma unroll
      for (int n = 0; n < 4; n++){
        int r = wc * 64 + n * 16 + (l & 15);
        bfv[n] = *(const bf16x8*)((const char*)Bs + r * 128 + (kb ^ ((r & 7) << 4)));
      }
      #pragma unroll
      for (int m = 0; m < 4; m++)
        #pragma unroll
        for (int n = 0; n < 4; n++)
          acc[m][n] = __builtin_amdgcn_mfma_f32_16x16x32_bf16(af[m], bfv[n], acc[m][n], 0, 0, 0);
    }
  }
  #pragma unroll
  for (int m = 0; m < 4; m++)
    #pragma unroll
    for (int n = 0; n < 4; n++)
      #pragma unroll
      for (int r4 = 0; r4 < 4; r4++){
        int row = ib * 128 + wr * 64 + m * 16 + p * 4 + r4;
        int col = nb * 128 + wc * 64 + n * 16 + (l & 15);
        C[(size_t)row * HID + col] = acc[m][n][r4];
      }
}

// ---------------- kernel 4: l, r and exp factors per (head,row) -------------
__global__ __launch_bounds__(256) void k_lr(const float* __restrict__ h,
                                            const float* __restrict__ a,
                                            float* __restrict__ L,  float* __restrict__ EL,
                                            float* __restrict__ EL2, float* __restrict__ R,
                                            float* __restrict__ ER, float* __restrict__ ER2){
  const int i = blockIdx.x;
  const int t = threadIdx.x;
  const int hd = t >> 5, l32 = t & 31;
  const int f = l32 << 2;
  const float4 hv = *(const float4*)(h + (size_t)i * HID + hd * DF + f);
  float pl = hv.x * a[(f + 0) * NH + hd] + hv.y * a[(f + 1) * NH + hd]
           + hv.z * a[(f + 2) * NH + hd] + hv.w * a[(f + 3) * NH + hd];
  float pr = hv.x * a[(128 + f + 0) * NH + hd] + hv.y * a[(128 + f + 1) * NH + hd]
           + hv.z * a[(128 + f + 2) * NH + hd] + hv.w * a[(128 + f + 3) * NH + hd];
  #pragma unroll
  for (int s = 1; s < 32; s <<= 1){
    pl += __shfl_xor(pl, s);
    pr += __shfl_xor(pr, s);
  }
  if (l32 == 0){
    int idx = hd * NN + i;
    L[idx]  = pl;            R[idx]  = pr;
    EL[idx] = expf(pl);      ER[idx] = expf(pr);
    EL2[idx]= expf(0.2f*pl); ER2[idx]= expf(0.2f*pr);
  }
}

// ---------------- kernel 5: HT[f][j] = bf16(h[j][f])  (transpose) -----------
__global__ __launch_bounds__(256) void k_tr(const float* __restrict__ h,
                                            u16* __restrict__ HT){
  __shared__ u16 T[64][80];  // stride 160B (16B-aligned rows)
  const int it = blockIdx.x & 63, ft = blockIdx.x >> 6;
  const int i0 = it * 64, f0 = ft * 64;
  const int t = threadIdx.x;
  const int r = t >> 4, c = (t & 15) << 2;
  #pragma unroll
  for (int q = 0; q < 4; q++){
    int row = r + q * 16;
    float4 v = *(const float4*)(h + (size_t)(i0 + row) * HID + f0 + c);
    T[c + 0][row] = f2bf(v.x);
    T[c + 1][row] = f2bf(v.y);
    T[c + 2][row] = f2bf(v.z);
    T[c + 3][row] = f2bf(v.w);
  }
  __syncthreads();
  const int fr = t >> 2, c0 = (t & 3) << 4;
  u16x8 v0 = *(const u16x8*)&T[fr][c0];
  u16x8 v1 = *(const u16x8*)&T[fr][c0 + 8];
  *(u16x8*)(HT + (size_t)(f0 + fr) * NN + i0 + c0)     = v0;
  *(u16x8*)(HT + (size_t)(f0 + fr) * NN + i0 + c0 + 8) = v1;
}

// ---------------- kernel 6: masked-softmax aggregation (partial over j) -----
// grid 1024 = (hd = b&7 -> XCD-local head) x 64 i-blocks x 2 j-halves.
// 256 threads = 4 waves, wave w owns rows i0 + w*16 .. +16, all 128 f,
// j in [jh*2048, jh*2048+2048). Writes RAW partial numerator (P) and
// denominator (D); k_comb divides + ELU. 4 blocks/CU -> 16 waves/CU.
__global__ __launch_bounds__(256) void k_agg(const u16* __restrict__ HT,
                                             const unsigned char* __restrict__ bm,
                                             const float* __restrict__ L,
                                             const float* __restrict__ EL,
                                             const float* __restrict__ EL2,
                                             const float* __restrict__ R,
                                             const float* __restrict__ ER,
                                             const float* __restrict__ ER2,
                                             float* __restrict__ P0,
                                             float* __restrict__ P1,
                                             float* __restrict__ D0,
                                             float* __restrict__ D1){
  __shared__ u16 Hs[2 * 8192];  // 2 x [128 f][64 j] bf16, swizzled
  const int b = blockIdx.x;
  const int hd = b & 7;             // head == XCD (b % 8)
  const int ib = (b >> 3) & 63;
  const int jh = b >> 9;
  const int i0 = ib * 64;
  const int jbase = jh * 2048;
  const int tid = threadIdx.x;
  const int w = tid >> 6, l = tid & 63;
  const int p = l >> 4;
  const int row_l = (w << 4) + (l & 15);
  const int gi = i0 + row_l;
  const float lv  = L  [hd * NN + gi];
  const float elv = EL [hd * NN + gi];
  const float el2v= EL2[hd * NN + gi];
  const float* Rr  = R   + hd * NN;
  const float* ERr = ER  + hd * NN;
  const float* GRr = ER2 + hd * NN;
  const unsigned long long* bmrow = (const unsigned long long*)(bm + (size_t)gi * 512);
  const u16* src = HT + (size_t)hd * DF * NN;
  float dsum = 0.f;
  f32x4 acc[8] = {};

  auto stage = [&](int d, int j0s){
    #pragma unroll
    for (int q = 0; q < 4; q++){
      int beta = ((q << 8) + tid) << 4;
      int fr = beta >> 7, inner = beta & 127;
      int gin = inner ^ ((fr & 7) << 4);
      gload16(src + (size_t)fr * NN + j0s + (gin >> 1), (char*)Hs + d * 16384 + beta);
    }
  };

  stage(0, jbase);
  __syncthreads();

  for (int jt = 0; jt < 32; ++jt){
    const int j0 = jbase + (jt << 6);
    const int cur = jt & 1;
    if (jt < 31) stage(cur ^ 1, j0 + 64);

    const unsigned long long bmv = bmrow[j0 >> 6];  // 64 adjacency bits, broadcast-ish

    // generate weight A-fragments for rows row_l, j in [j0, j0+64)
    bf16x8 af[2];
    #pragma unroll
    for (int kk = 0; kk < 2; kk++){
      const int jb = j0 + (kk << 5) + (p << 3);
      const float4 rv0 = *(const float4*)(Rr  + jb);
      const float4 rv1 = *(const float4*)(Rr  + jb + 4);
      const float4 ev0 = *(const float4*)(ERr + jb);
      const float4 ev1 = *(const float4*)(ERr + jb + 4);
      const float4 gv0 = *(const float4*)(GRr + jb);
      const float4 gv1 = *(const float4*)(GRr + jb + 4);
      const unsigned int bbits = (unsigned int)(bmv >> (((kk << 2) + p) << 3)) & 0xffu;
      const float rarr[8] = {rv0.x, rv0.y, rv0.z, rv0.w, rv1.x, rv1.y, rv1.z, rv1.w};
      const float earr[8] = {ev0.x, ev0.y, ev0.z, ev0.w, ev1.x, ev1.y, ev1.z, ev1.w};
      const float garr[8] = {gv0.x, gv0.y, gv0.z, gv0.w, gv1.x, gv1.y, gv1.z, gv1.w};
      bf16x8 av;
      #pragma unroll
      for (int e = 0; e < 8; e++){
        float s  = lv + rarr[e];
        bool pos = s > 0.f;
        float w1 = pos ? elv : el2v;
        float w2 = pos ? earr[e] : garr[e];
        float wq = w1 * w2;
        wq = ((bbits >> e) & 1u) ? wq : 0.f;
        dsum += wq;
        av[e] = (short)f2bf(wq);
      }
      af[kk] = av;
    }

    // MFMA: acc[n] += W_frag x H^T fragments
    const char* hb = (const char*)Hs + cur * 16384;
    #pragma unroll
    for (int kk = 0; kk < 2; kk++){
      const int kb = ((kk << 5) + (p << 3)) << 1;
      #pragma unroll
      for (int n = 0; n < 8; n++){
        const int fr = (n << 4) + (l & 15);
        bf16x8 bfr = *(const bf16x8*)(hb + fr * 128 + (kb ^ ((fr & 7) << 4)));
        acc[n] = __builtin_amdgcn_mfma_f32_16x16x32_bf16(af[kk], bfr, acc[n], 0, 0, 0);
      }
    }
    __syncthreads();
  }

  // full row denominators for this j-half: sum the 4 k-octet lane groups
  dsum += __shfl_xor(dsum, 16);
  dsum += __shfl_xor(dsum, 32);

  float* P = jh ? P1 : P0;
  float* D = jh ? D1 : D0;
  if (l < 16) D[hd * NN + i0 + (w << 4) + l] = dsum;

  const int rowbase = i0 + (w << 4) + (p << 2);
  #pragma unroll
  for (int r4 = 0; r4 < 4; r4++){
    const int grow = rowbase + r4;
    float* orow = P + (size_t)grow * HID + hd * DF;
    #pragma unroll
    for (int n = 0; n < 8; n++)
      orow[(n << 4) + (l & 15)] = acc[n][r4];
  }
}

// ---------------- kernel 7: combine j-halves, divide, ELU -------------------
__global__ __launch_bounds__(256) void k_comb(const float* __restrict__ P1,
                                              const float* __restrict__ D0,
                                              const float* __restrict__ D1,
                                              float* __restrict__ out){
  const int idx = blockIdx.x * 256 + threadIdx.x;  // one float4 each
  const int i  = idx >> 8;          // 256 float4 per row
  const int c4 = idx & 255;
  const int hd = c4 >> 5;           // 32 float4 per head
  const float d = D0[hd * NN + i] + D1[hd * NN + i];
  const float rinv = 1.0f / d;
  float4 a0 = ((const float4*)out)[idx];
  float4 a1 = ((const float4*)P1)[idx];
  float4 v;
  v.x = (a0.x + a1.x) * rinv;
  v.y = (a0.y + a1.y) * rinv;
  v.z = (a0.z + a1.z) * rinv;
  v.w = (a0.w + a1.w) * rinv;
  v.x = v.x > 0.f ? v.x : (expf(v.x) - 1.0f);
  v.y = v.y > 0.f ? v.y : (expf(v.y) - 1.0f);
  v.z = v.z > 0.f ? v.z : (expf(v.z) - 1.0f);
  v.w = v.w > 0.f ? v.w : (expf(v.w) - 1.0f);
  ((float4*)out)[idx] = v;
}

extern "C" void kernel_launch(void* const* d_in, const int* in_sizes, int n_in,
                              void* d_out, int out_size, void* d_ws, size_t ws_size,
                              hipStream_t stream) {
  const float* X   = (const float*)d_in[0];
  const int*   adj = (const int*)d_in[1];
  const float* W   = (const float*)d_in[2];
  const float* a   = (const float*)d_in[3];
  float* out = (float*)d_out;

  char* ws = (char*)d_ws;
  size_t off = 0;
  float* h  = (float*)(ws + off);        off += (size_t)NN * HID * 4;   // 16.78 MB
  u16*   A2 = (u16*)(ws + off);          off += (size_t)NN * KIN * 2;   //  4.19 MB
  u16*   WT = (u16*)(ws + off);          off += (size_t)HID * KIN * 2;  //  1.05 MB
  u16*   HT = (u16*)(ws + off);          off += (size_t)HID * NN * 2;   //  8.39 MB
  unsigned char* bmp = (unsigned char*)(ws + off); off += (size_t)NN * 512; // 2.10 MB
  float* L   = (float*)(ws + off);       off += (size_t)NH * NN * 4;
  float* EL  = (float*)(ws + off);       off += (size_t)NH * NN * 4;
  float* EL2 = (float*)(ws + off);       off += (size_t)NH * NN * 4;
  float* R   = (float*)(ws + off);       off += (size_t)NH * NN * 4;
  float* ER  = (float*)(ws + off);       off += (size_t)NH * NN * 4;
  float* ER2 = (float*)(ws + off);       off += (size_t)NH * NN * 4;    // total ~33.3 MB

  // Overlays (dead after k_gemm / k_tr):
  float* P0 = out;                 // j-half 0 partial numerator -> d_out
  float* P1 = h;                   // j-half 1 partial numerator -> h buffer
  float* D0 = (float*)A2;          // partial denominators -> A2 buffer
  float* D1 = D0 + NH * NN;

  k_pack<<<dim3(NN * NN / 256), dim3(256), 0, stream>>>(adj, (unsigned long long*)bmp);
  k_conv<<<dim3(NN * KIN / 256), dim3(256), 0, stream>>>(X, W, A2, WT);
  k_gemm<<<dim3(256), dim3(256), 0, stream>>>(A2, WT, h);
  k_lr  <<<dim3(NN), dim3(256), 0, stream>>>(h, a, L, EL, EL2, R, ER, ER2);
  k_tr  <<<dim3(1024), dim3(256), 0, stream>>>(h, HT);
  k_agg <<<dim3(1024), dim3(256), 0, stream>>>(HT, bmp, L, EL, EL2, R, ER, ER2, P0, P1, D0, D1);
  k_comb<<<dim3(NN * HID / 1024), dim3(256), 0, stream>>>(P1, D0, D1, out);
}

// Round 3
// 143.068 us; speedup vs baseline: 1.6925x; 1.2757x over previous
//
#include <hip/hip_runtime.h>
#include <stdint.h>

#define NN 4096
#define KIN 512
#define NH 8
#define DF 128
#define HID 1024

typedef __attribute__((ext_vector_type(8))) short bf16x8;
typedef __attribute__((ext_vector_type(4))) float f32x4;
typedef __attribute__((ext_vector_type(8))) unsigned short u16x8;
typedef unsigned short u16;

__device__ __forceinline__ u16 f2bf(float x){
  unsigned int u = __float_as_uint(x);
  return (u16)((u + 0x7fffu + ((u >> 16) & 1u)) >> 16);
}

__device__ __forceinline__ float fexp2(float x){
#if __has_builtin(__builtin_amdgcn_exp2f)
  return __builtin_amdgcn_exp2f(x);
#else
  return exp2f(x);
#endif
}

__device__ __forceinline__ void gload16(const void* g, void* lds){
  __builtin_amdgcn_global_load_lds(
      (const __attribute__((address_space(1))) unsigned int*)g,
      (__attribute__((address_space(3))) unsigned int*)lds, 16, 0, 0);
}

// ---------------- kernel 1: pack adjacency to bitmask (1 byte/thread) -------
__global__ __launch_bounds__(256) void k_pack(const int4* __restrict__ adj,
                                              unsigned char* __restrict__ bm){
  int idx = blockIdx.x * 256 + threadIdx.x;   // byte index, NN*NN/8 total
  int4 a = adj[idx * 2];
  int4 b = adj[idx * 2 + 1];
  unsigned int m = (a.x != 0)        | ((a.y != 0) << 1) | ((a.z != 0) << 2) |
                   ((a.w != 0) << 3) | ((b.x != 0) << 4) | ((b.y != 0) << 5) |
                   ((b.z != 0) << 6) | ((b.w != 0) << 7);
  bm[idx] = (unsigned char)m;
}

// ---------------- kernel 2: bf16 convert X -> A2, W^T -> WT -----------------
__global__ __launch_bounds__(256) void k_conv(const float* __restrict__ X,
                                              const float* __restrict__ W,
                                              u16* __restrict__ A2,
                                              u16* __restrict__ WT){
  int idx = blockIdx.x * 256 + threadIdx.x;
  if (idx < NN * KIN) A2[idx] = f2bf(X[idx]);
  if (idx < HID * KIN){
    int n = idx / KIN, k = idx % KIN;
    WT[idx] = f2bf(W[k * HID + n]);
  }
}

// ---------------- kernel 3: h = X @ W  (bf16 MFMA, 128x128 tile) ------------
__global__ __launch_bounds__(256) void k_gemm(const u16* __restrict__ A2,
                                              const u16* __restrict__ BT,
                                              float* __restrict__ C){
  __shared__ u16 As[8192], Bs[8192];  // [128 rows][64 k], XOR-swizzled rows
  const int tid = threadIdx.x;
  const int l = tid & 63, w = tid >> 6;
  const int wr = w >> 1, wc = w & 1;
  const int ib = blockIdx.x >> 3, nb = blockIdx.x & 7;
  const int p = l >> 4;
  f32x4 acc[4][4] = {};
  for (int k0 = 0; k0 < KIN; k0 += 64){
    __syncthreads();
    #pragma unroll
    for (int q = 0; q < 4; q++){
      int beta = ((q << 8) + tid) << 4;
      int row = beta >> 7, inner = beta & 127;
      int gin = inner ^ ((row & 7) << 4);
      gload16(A2 + (size_t)(ib * 128 + row) * KIN + k0 + (gin >> 1), (char*)As + beta);
      gload16(BT + (size_t)(nb * 128 + row) * KIN + k0 + (gin >> 1), (char*)Bs + beta);
    }
    __syncthreads();
    #pragma unroll
    for (int kk = 0; kk < 2; kk++){
      bf16x8 af[4], bfv[4];
      const int kb = ((kk << 5) + (p << 3)) << 1;
      #pragma unroll
      for (int m = 0; m < 4; m++){
        int r = wr * 64 + m * 16 + (l & 15);
        af[m] = *(const bf16x8*)((const char*)As + r * 128 + (kb ^ ((r & 7) << 4)));
      }
      #pragma unroll
      for (int n = 0; n < 4; n++){
        int r = wc * 64 + n * 16 + (l & 15);
        bfv[n] = *(const bf16x8*)((const char*)Bs + r * 128 + (kb ^ ((r & 7) << 4)));
      }
      #pragma unroll
      for (int m = 0; m < 4; m++)
        #pragma unroll
        for (int n = 0; n < 4; n++)
          acc[m][n] = __builtin_amdgcn_mfma_f32_16x16x32_bf16(af[m], bfv[n], acc[m][n], 0, 0, 0);
    }
  }
  #pragma unroll
  for (int m = 0; m < 4; m++)
    #pragma unroll
    for (int n = 0; n < 4; n++)
      #pragma unroll
      for (int r4 = 0; r4 < 4; r4++){
        int row = ib * 128 + wr * 64 + m * 16 + p * 4 + r4;
        int col = nb * 128 + wc * 64 + n * 16 + (l & 15);
        C[(size_t)row * HID + col] = acc[m][n][r4];
      }
}

// ---------------- kernel 4: Lg = l*log2e, Rg = r*log2e per (head,row) -------
__global__ __launch_bounds__(256) void k_lr(const float* __restrict__ h,
                                            const float* __restrict__ a,
                                            float* __restrict__ Lg,
                                            float* __restrict__ Rg){
  const int i = blockIdx.x;
  const int t = threadIdx.x;
  const int hd = t >> 5, l32 = t & 31;
  const int f = l32 << 2;
  const float4 hv = *(const float4*)(h + (size_t)i * HID + hd * DF + f);
  float pl = hv.x * a[(f + 0) * NH + hd] + hv.y * a[(f + 1) * NH + hd]
           + hv.z * a[(f + 2) * NH + hd] + hv.w * a[(f + 3) * NH + hd];
  float pr = hv.x * a[(128 + f + 0) * NH + hd] + hv.y * a[(128 + f + 1) * NH + hd]
           + hv.z * a[(128 + f + 2) * NH + hd] + hv.w * a[(128 + f + 3) * NH + hd];
  #pragma unroll
  for (int s = 1; s < 32; s <<= 1){
    pl += __shfl_xor(pl, s);
    pr += __shfl_xor(pr, s);
  }
  if (l32 == 0){
    int idx = hd * NN + i;
    Lg[idx] = pl * 1.44269504089f;
    Rg[idx] = pr * 1.44269504089f;
  }
}

// ---------------- kernel 5: HT[f][j] = bf16(h[j][f])  (transpose) -----------
__global__ __launch_bounds__(256) void k_tr(const float* __restrict__ h,
                                            u16* __restrict__ HT){
  __shared__ u16 T[64][80];  // stride 160B (16B-aligned rows)
  const int it = blockIdx.x & 63, ft = blockIdx.x >> 6;
  const int i0 = it * 64, f0 = ft * 64;
  const int t = threadIdx.x;
  const int r = t >> 4, c = (t & 15) << 2;
  #pragma unroll
  for (int q = 0; q < 4; q++){
    int row = r + q * 16;
    float4 v = *(const float4*)(h + (size_t)(i0 + row) * HID + f0 + c);
    T[c + 0][row] = f2bf(v.x);
    T[c + 1][row] = f2bf(v.y);
    T[c + 2][row] = f2bf(v.z);
    T[c + 3][row] = f2bf(v.w);
  }
  __syncthreads();
  const int fr = t >> 2, c0 = (t & 3) << 4;
  u16x8 v0 = *(const u16x8*)&T[fr][c0];
  u16x8 v1 = *(const u16x8*)&T[fr][c0 + 8];
  *(u16x8*)(HT + (size_t)(f0 + fr) * NN + i0 + c0)     = v0;
  *(u16x8*)(HT + (size_t)(f0 + fr) * NN + i0 + c0 + 8) = v1;
}

// ---------------- kernel 6: masked-softmax aggregation (partial over j) -----
// grid 1024 = (hd = b&7 -> XCD-local head) x 64 i-blocks x 2 j-halves.
// 256 threads = 4 waves, wave w owns rows i0 + w*16 .. +16, all 128 f.
// Weight w(i,j) = exp2(max(s, 0.2s)), s = Lg[i]+Rg[j]; masked -> exp2(-131072)=0.
__global__ __launch_bounds__(256) void k_agg(const u16* __restrict__ HT,
                                             const unsigned char* __restrict__ bm,
                                             const float* __restrict__ Lg,
                                             const float* __restrict__ Rg,
                                             float* __restrict__ P0,
                                             float* __restrict__ P1,
                                             float* __restrict__ D0,
                                             float* __restrict__ D1){
  __shared__ u16 Hs[2 * 8192];  // 2 x [128 f][64 j] bf16, swizzled
  const int b = blockIdx.x;
  const int hd = b & 7;             // head == XCD (b % 8)
  const int ib = (b >> 3) & 63;
  const int jh = b >> 9;
  const int i0 = ib * 64;
  const int jbase = jh * 2048;
  const int tid = threadIdx.x;
  const int w = tid >> 6, l = tid & 63;
  const int p = l >> 4;
  const int row_l = (w << 4) + (l & 15);
  const int gi = i0 + row_l;
  const float lgv = Lg[hd * NN + gi];
  const float* Rr = Rg + hd * NN;
  const unsigned long long* bmrow = (const unsigned long long*)(bm + (size_t)gi * 512);
  const u16* src = HT + (size_t)hd * DF * NN;
  float dsA = 0.f, dsB = 0.f;
  f32x4 acc[8] = {};

  auto stage = [&](int d, int j0s){
    #pragma unroll
    for (int q = 0; q < 4; q++){
      int beta = ((q << 8) + tid) << 4;
      int fr = beta >> 7, inner = beta & 127;
      int gin = inner ^ ((fr & 7) << 4);
      gload16(src + (size_t)fr * NN + j0s + (gin >> 1), (char*)Hs + d * 16384 + beta);
    }
  };

  stage(0, jbase);
  __syncthreads();

  for (int jt = 0; jt < 32; ++jt){
    const int j0 = jbase + (jt << 6);
    const int cur = jt & 1;
    if (jt < 31) stage(cur ^ 1, j0 + 64);

    const unsigned long long bmv = bmrow[j0 >> 6];  // 64 adjacency bits

    // generate weight A-fragments for row gi, j in [j0, j0+64)
    bf16x8 af[2];
    #pragma unroll
    for (int kk = 0; kk < 2; kk++){
      const int jb = j0 + (kk << 5) + (p << 3);
      const float4 rv0 = *(const float4*)(Rr + jb);
      const float4 rv1 = *(const float4*)(Rr + jb + 4);
      const unsigned int bbits = (unsigned int)(bmv >> (((kk << 2) + p) << 3)) & 0xffu;
      const float r8[8] = {rv0.x, rv0.y, rv0.z, rv0.w, rv1.x, rv1.y, rv1.z, rv1.w};
      float w8[8];
      #pragma unroll
      for (int e = 0; e < 8; e++){
        float s = lgv + r8[e];
        float t = fmaxf(s, 0.2f * s);
        t = ((bbits >> e) & 1u) ? t : -131072.f;
        float wv = fexp2(t);
        if (e & 1) dsB += wv; else dsA += wv;
        w8[e] = wv;
      }
      union { bf16x8 v; unsigned int u[4]; } av;
      #pragma unroll
      for (int q = 0; q < 4; q++)
        asm("v_cvt_pk_bf16_f32 %0, %1, %2"
            : "=v"(av.u[q]) : "v"(w8[2 * q]), "v"(w8[2 * q + 1]));
      af[kk] = av.v;
    }

    // MFMA: acc[n] += W_frag x H^T fragments
    const char* hb = (const char*)Hs + cur * 16384;
    #pragma unroll
    for (int kk = 0; kk < 2; kk++){
      const int kb = ((kk << 5) + (p << 3)) << 1;
      #pragma unroll
      for (int n = 0; n < 8; n++){
        const int fr = (n << 4) + (l & 15);
        bf16x8 bfr = *(const bf16x8*)(hb + fr * 128 + (kb ^ ((fr & 7) << 4)));
        acc[n] = __builtin_amdgcn_mfma_f32_16x16x32_bf16(af[kk], bfr, acc[n], 0, 0, 0);
      }
    }
    __syncthreads();
  }

  // full row denominators for this j-half: sum the 4 k-octet lane groups
  float dsum = dsA + dsB;
  dsum += __shfl_xor(dsum, 16);
  dsum += __shfl_xor(dsum, 32);

  float* P = jh ? P1 : P0;
  float* D = jh ? D1 : D0;
  if (l < 16) D[hd * NN + i0 + (w << 4) + l] = dsum;

  const int rowbase = i0 + (w << 4) + (p << 2);
  #pragma unroll
  for (int r4 = 0; r4 < 4; r4++){
    const int grow = rowbase + r4;
    float* orow = P + (size_t)grow * HID + hd * DF;
    #pragma unroll
    for (int n = 0; n < 8; n++)
      orow[(n << 4) + (l & 15)] = acc[n][r4];
  }
}

// ---------------- kernel 7: combine j-halves, divide, ELU -------------------
__global__ __launch_bounds__(256) void k_comb(const float* __restrict__ P1,
                                              const float* __restrict__ D0,
                                              const float* __restrict__ D1,
                                              float* __restrict__ out){
  const int idx = blockIdx.x * 256 + threadIdx.x;  // one float4 each
  const int i  = idx >> 8;          // 256 float4 per row
  const int c4 = idx & 255;
  const int hd = c4 >> 5;           // 32 float4 per head
  const float d = D0[hd * NN + i] + D1[hd * NN + i];
  const float rinv = 1.0f / d;
  float4 a0 = ((const float4*)out)[idx];
  float4 a1 = ((const float4*)P1)[idx];
  float4 v;
  v.x = (a0.x + a1.x) * rinv;
  v.y = (a0.y + a1.y) * rinv;
  v.z = (a0.z + a1.z) * rinv;
  v.w = (a0.w + a1.w) * rinv;
  v.x = v.x > 0.f ? v.x : (expf(v.x) - 1.0f);
  v.y = v.y > 0.f ? v.y : (expf(v.y) - 1.0f);
  v.z = v.z > 0.f ? v.z : (expf(v.z) - 1.0f);
  v.w = v.w > 0.f ? v.w : (expf(v.w) - 1.0f);
  ((float4*)out)[idx] = v;
}

extern "C" void kernel_launch(void* const* d_in, const int* in_sizes, int n_in,
                              void* d_out, int out_size, void* d_ws, size_t ws_size,
                              hipStream_t stream) {
  const float* X   = (const float*)d_in[0];
  const int*   adj = (const int*)d_in[1];
  const float* W   = (const float*)d_in[2];
  const float* a   = (const float*)d_in[3];
  float* out = (float*)d_out;

  char* ws = (char*)d_ws;
  size_t off = 0;
  float* h  = (float*)(ws + off);        off += (size_t)NN * HID * 4;   // 16.78 MB
  u16*   A2 = (u16*)(ws + off);          off += (size_t)NN * KIN * 2;   //  4.19 MB
  u16*   WT = (u16*)(ws + off);          off += (size_t)HID * KIN * 2;  //  1.05 MB
  u16*   HT = (u16*)(ws + off);          off += (size_t)HID * NN * 2;   //  8.39 MB
  unsigned char* bmp = (unsigned char*)(ws + off); off += (size_t)NN * 512; // 2.10 MB
  float* Lg = (float*)(ws + off);        off += (size_t)NH * NN * 4;
  float* Rg = (float*)(ws + off);        off += (size_t)NH * NN * 4;    // total ~32.8 MB

  // Overlays (dead after k_gemm / k_tr):
  float* P0 = out;                 // j-half 0 partial numerator -> d_out
  float* P1 = h;                   // j-half 1 partial numerator -> h buffer
  float* D0 = (float*)A2;          // partial denominators -> A2 buffer
  float* D1 = D0 + NH * NN;

  k_pack<<<dim3(NN * NN / 8 / 256), dim3(256), 0, stream>>>((const int4*)adj, bmp);
  k_conv<<<dim3(NN * KIN / 256), dim3(256), 0, stream>>>(X, W, A2, WT);
  k_gemm<<<dim3(256), dim3(256), 0, stream>>>(A2, WT, h);
  k_lr  <<<dim3(NN), dim3(256), 0, stream>>>(h, a, Lg, Rg);
  k_tr  <<<dim3(1024), dim3(256), 0, stream>>>(h, HT);
  k_agg <<<dim3(1024), dim3(256), 0, stream>>>(HT, bmp, Lg, Rg, P0, P1, D0, D1);
  k_comb<<<dim3(NN * HID / 1024), dim3(256), 0, stream>>>(P1, D0, D1, out);
}